// Round 7
// baseline (2901.267 us; speedup 1.0000x reference)
//
#include <hip/hip_runtime.h>
#include <hip/hip_cooperative_groups.h>
#include <hip/hip_fp16.h>
#include <math.h>

namespace cg = cooperative_groups;

#define B_ 64
#define N_ 512
#define H_ 32
#define E_ 4
#define NSTEPS 5
#define KTOT 2048       // N_*E_
#define KSPLIT 8
#define KCHUNK 256      // fallback path
#define ASLAB (B_*N_*H_)

typedef _Float16 half8 __attribute__((ext_vector_type(8)));
typedef float   f32x4 __attribute__((ext_vector_type(4)));

struct P2 {
    const float *x, *a, *m;
    const float *W_in, *b_in, *W_out, *b_out;
    const float *Wz, *bz, *Wr, *br, *Wt, *bt;
    const float *W1, *b1, *W2, *b2;
    float *out;
    float *h;
};

// ================================================================ fused steps
// 256 blocks x 1024 threads (1 block/CU; LDS=136KB forces this anyway).
// __launch_bounds__(1024,4): 4 waves/EU == the real occupancy -> VGPR cap 128
// (round 6 ran at 64 VGPR and spilled ~510 MB/step to scratch).
__global__ __launch_bounds__(1024, 4) void k_steps(P2 p) {
    cg::grid_group grid = cg::this_grid();
    const int bid = blockIdx.x;
    const int b  = bid >> 2, nb = bid & 3;
    const int R0 = nb * 128;
    const int tid = threadIdx.x;
    const int lane = tid & 63;
    const int wv   = tid >> 6;         // 0..15
    const int l15  = lane & 15, quad = lane >> 4;
    const int rowtile = wv >> 1, coltile = wv & 1;
    const int ig = tid & 31, rg = tid >> 5;   // fold/gate mapping (rg 0..31)

    __shared__ __align__(16) char hT[2][32768];   // [plane][c 32][n' 512 x2B] swz
    __shared__ float Gs[128][32];
    __shared__ float aLds[128][64];
    __shared__ float msumL[128][8];
    __shared__ float rhL[32][32];
    __shared__ float hOld[128][32];

    const size_t hbase = (size_t)b * N_ * H_;

    for (int s = 0; s < NSTEPS; s++) {
        if (s > 0) grid.sync();
        const float* hsrc = (s == 0 ? p.x : p.h) + hbase;

        // ---- stage hT (full 512 rows of h[b], hi/lo fp16, XOR-swizzled)
        for (int i = tid; i < 4096; i += 1024) {
            int np = i >> 3, c4 = i & 7;
            f32x4 v = *(const f32x4*)(hsrc + (size_t)np * H_ + c4 * 4);
#pragma unroll
            for (int j = 0; j < 4; j++) {
                int c = c4 * 4 + j;
                float vv = v[j];
                _Float16 hh = (_Float16)vv;
                _Float16 ll = (_Float16)(vv - (float)hh);
                int off = c * 1024 + ((np * 2) ^ ((c & 7) << 4));
                *(_Float16*)(&hT[0][0] + off) = hh;
                *(_Float16*)(&hT[1][0] + off) = ll;
            }
        }
        // ---- stage own rows' h for the gate
        for (int i = tid; i < 4096; i += 1024)
            hOld[i >> 5][i & 31] = hsrc[(size_t)(R0 + (i >> 5)) * H_ + (i & 31)];
        __syncthreads();

        float aReg[2][4];
#pragma unroll
        for (int d2 = 0; d2 < 2; d2++)
#pragma unroll
            for (int rx = 0; rx < 4; rx++) aReg[d2][rx] = 0.f;

#pragma unroll
        for (int dir = 0; dir < 2; dir++) {
            const float* Wf = dir ? p.W_out : p.W_in;
            const float* bf = dir ? p.b_out : p.b_in;
            for (int e = 0; e < 4; e++) {
                const float* mrow = p.m
                    + ((size_t)(b * N_ + R0 + rowtile * 16 + l15)) * (2 * KTOT)
                    + (size_t)dir * KTOT + e * 512;
                const int brow = coltile * 16 + l15;
                const int bswz = (brow & 7) << 4;
                const int boff = brow * 1024;
                f32x4 acc = {0.f, 0.f, 0.f, 0.f};
                float sac = 0.f;
#pragma unroll 2
                for (int kk = 0; kk < 16; kk++) {
                    int k0 = kk * 32 + quad * 8;
                    f32x4 a0 = *(const f32x4*)(mrow + k0);
                    f32x4 a1 = *(const f32x4*)(mrow + k0 + 4);
                    half8 Ahi, Alo;
#pragma unroll
                    for (int j = 0; j < 4; j++) {
                        float v0 = a0[j], v1 = a1[j];
                        _Float16 h0 = (_Float16)v0, h1 = (_Float16)v1;
                        Ahi[j]     = h0;
                        Ahi[j + 4] = h1;
                        Alo[j]     = (_Float16)(v0 - (float)h0);
                        Alo[j + 4] = (_Float16)(v1 - (float)h1);
                    }
                    if (s == 0)
                        sac += a0[0]+a0[1]+a0[2]+a0[3]+a1[0]+a1[1]+a1[2]+a1[3];
                    int off = boff + ((k0 * 2) ^ bswz);
                    half8 Bhi = *(const half8*)(&hT[0][0] + off);
                    half8 Blo = *(const half8*)(&hT[1][0] + off);
                    acc = __builtin_amdgcn_mfma_f32_16x16x32_f16(Ahi, Bhi, acc, 0, 0, 0);
                    acc = __builtin_amdgcn_mfma_f32_16x16x32_f16(Ahi, Blo, acc, 0, 0, 0);
                    acc = __builtin_amdgcn_mfma_f32_16x16x32_f16(Alo, Bhi, acc, 0, 0, 0);
                }
                if (s == 0 && coltile == 0) {
                    sac += __shfl_xor(sac, 16);
                    sac += __shfl_xor(sac, 32);
                    if (quad == 0) msumL[rowtile * 16 + l15][dir * 4 + e] = sac;
                }
#pragma unroll
                for (int r = 0; r < 4; r++)
                    Gs[rowtile * 16 + quad * 4 + r][coltile * 16 + l15] = acc[r];
                __syncthreads();

                // fold: a[row][ig] += msum*bias + Gs[row] . W[ig*4+e]
                const float* wrow = Wf + (size_t)(ig * 4 + e) * 32;
                float msb = bf[ig * 4 + e];
#pragma unroll
                for (int rx = 0; rx < 4; rx++) {
                    int row = rg + rx * 32;
                    const f32x4* g  = (const f32x4*)Gs[row];
                    const f32x4* wq = (const f32x4*)wrow;
                    float t = msumL[row][dir * 4 + e] * msb;
#pragma unroll
                    for (int q = 0; q < 8; q++) {
                        f32x4 gv = g[q], wvv = wq[q];
                        t += gv[0]*wvv[0] + gv[1]*wvv[1] + gv[2]*wvv[2] + gv[3]*wvv[3];
                    }
                    aReg[dir][rx] += t;
                }
                __syncthreads();   // Gs reuse next e
            }
#pragma unroll
            for (int rx = 0; rx < 4; rx++)
                aLds[rg + rx * 32][dir * 32 + ig] = aReg[dir][rx];
        }
        __syncthreads();

        // ---- GRU gate: 4 passes of 32 rows (32 threads per row)
        for (int ps = 0; ps < 4; ps++) {
            int row = ps * 32 + rg;
            float az = p.bz[ig], ar = p.br[ig];
            const f32x4* wz = (const f32x4*)(p.Wz + (size_t)ig * 96);
            const f32x4* wr = (const f32x4*)(p.Wr + (size_t)ig * 96);
            const f32x4* ca = (const f32x4*)aLds[row];
            const f32x4* ch = (const f32x4*)hOld[row];
#pragma unroll
            for (int kc = 0; kc < 16; kc++) {
                f32x4 cv = ca[kc], z1 = wz[kc], r1 = wr[kc];
                az += cv[0]*z1[0] + cv[1]*z1[1] + cv[2]*z1[2] + cv[3]*z1[3];
                ar += cv[0]*r1[0] + cv[1]*r1[1] + cv[2]*r1[2] + cv[3]*r1[3];
            }
#pragma unroll
            for (int kc = 0; kc < 8; kc++) {
                f32x4 cv = ch[kc], z1 = wz[16 + kc], r1 = wr[16 + kc];
                az += cv[0]*z1[0] + cv[1]*z1[1] + cv[2]*z1[2] + cv[3]*z1[3];
                ar += cv[0]*r1[0] + cv[1]*r1[1] + cv[2]*r1[2] + cv[3]*r1[3];
            }
            float zg    = 1.f / (1.f + __expf(-az));
            float rgate = 1.f / (1.f + __expf(-ar));
            float hold  = hOld[row][ig];
            rhL[rg][ig] = rgate * hold;
            __syncthreads();
            float at = p.bt[ig];
            const f32x4* wt = (const f32x4*)(p.Wt + (size_t)ig * 96);
#pragma unroll
            for (int kc = 0; kc < 16; kc++) {
                f32x4 cv = ca[kc], t1 = wt[kc];
                at += cv[0]*t1[0] + cv[1]*t1[1] + cv[2]*t1[2] + cv[3]*t1[3];
            }
            const f32x4* rr = (const f32x4*)rhL[rg];
#pragma unroll
            for (int kc = 0; kc < 8; kc++) {
                f32x4 cv = rr[kc], t1 = wt[16 + kc];
                at += cv[0]*t1[0] + cv[1]*t1[1] + cv[2]*t1[2] + cv[3]*t1[3];
            }
            float hh2  = tanhf(at);
            float hnew = (1.f - zg) * hold + zg * hh2;
            p.h[hbase + (size_t)(R0 + row) * H_ + ig] = hnew;
            hOld[row][ig] = hnew;   // all hOld reads for this pass done pre-sync
            __syncthreads();        // rhL reuse next pass
        }
    }

    // ---- readout (own rows only; hOld holds final h)
    for (int ps = 0; ps < 4; ps++) {
        int row = ps * 32 + rg;
        float acc = p.b1[ig];
        const float* w1r = p.W1 + (size_t)ig * 33;
#pragma unroll
        for (int i2 = 0; i2 < 32; i2++) acc += hOld[row][i2] * w1r[i2];
        acc += p.a[(size_t)b * N_ + R0 + row] * w1r[32];
        float o = tanhf(acc) * p.W2[ig];
#pragma unroll
        for (int off = 16; off; off >>= 1) o += __shfl_xor(o, off, 32);
        if (ig == 0) p.out[(size_t)b * N_ + R0 + row] = o + p.b2[0];
    }
}

// ================================================================ FALLBACK
// (verbatim round-4 kernels, used only if cooperative launch fails)
__global__ __launch_bounds__(256) void k_init_h(const float* __restrict__ x,
                                                float* __restrict__ h) {
    int i = blockIdx.x * blockDim.x + threadIdx.x;
    ((f32x4*)h)[i] = ((const f32x4*)x)[i];
}

__global__ __launch_bounds__(256) void k_s(const float* __restrict__ hstate,
                                           const float* __restrict__ W_in,
                                           const float* __restrict__ b_in,
                                           const float* __restrict__ W_out,
                                           const float* __restrict__ b_out,
                                           _Float16* __restrict__ sT_in_hi,
                                           _Float16* __restrict__ sT_in_lo,
                                           _Float16* __restrict__ sT_out_hi,
                                           _Float16* __restrict__ sT_out_lo) {
    int b  = blockIdx.x >> 3;
    int n0 = (blockIdx.x & 7) * 64;
    int lane = threadIdx.x & 63;
    int w = __builtin_amdgcn_readfirstlane((int)(threadIdx.x >> 6));
    int n = n0 + lane;

    const float* hrow = hstate + ((size_t)b * N_ + n) * H_;
    f32x4 hv[8];
#pragma unroll
    for (int c = 0; c < 8; c++) hv[c] = ((const f32x4*)hrow)[c];

#pragma unroll 4
    for (int o = 0; o < 32; o++) {
        int he = w * 32 + o;
        const f32x4* wr = (const f32x4*)(W_in + (size_t)he * H_);
        float acc = b_in[he];
#pragma unroll
        for (int c = 0; c < 8; c++) {
            f32x4 wv = wr[c];
            acc += hv[c][0]*wv[0] + hv[c][1]*wv[1] + hv[c][2]*wv[2] + hv[c][3]*wv[3];
        }
        int hh = he >> 2, e = he & 3;
        size_t idx = ((size_t)b * H_ + hh) * KTOT + e * N_ + n;
        _Float16 hi = (_Float16)acc;
        sT_in_hi[idx] = hi;
        sT_in_lo[idx] = (_Float16)(acc - (float)hi);
    }
#pragma unroll 4
    for (int o = 0; o < 32; o++) {
        int he = w * 32 + o;
        const f32x4* wr = (const f32x4*)(W_out + (size_t)he * H_);
        float acc = b_out[he];
#pragma unroll
        for (int c = 0; c < 8; c++) {
            f32x4 wv = wr[c];
            acc += hv[c][0]*wv[0] + hv[c][1]*wv[1] + hv[c][2]*wv[2] + hv[c][3]*wv[3];
        }
        int hh = he >> 2, e = he & 3;
        size_t idx = ((size_t)b * H_ + hh) * KTOT + e * N_ + n;
        _Float16 hi = (_Float16)acc;
        sT_out_hi[idx] = hi;
        sT_out_lo[idx] = (_Float16)(acc - (float)hi);
    }
}

__global__ __launch_bounds__(256) void k_einsum_l(const float* __restrict__ m,
                                                  const _Float16* __restrict__ sT_in_hi,
                                                  const _Float16* __restrict__ sT_in_lo,
                                                  const _Float16* __restrict__ sT_out_hi,
                                                  const _Float16* __restrict__ sT_out_lo,
                                                  float* __restrict__ apart) {
    int split = blockIdx.x;
    int b     = blockIdx.y;
    int dir   = blockIdx.z;
    int tid   = threadIdx.x;
    int w     = tid >> 6;
    int lane  = tid & 63;
    int l15   = lane & 15;
    int quad  = lane >> 4;

    __shared__ __align__(16) char smem[32768];

    const _Float16* sHi = (dir ? sT_out_hi : sT_in_hi)
                          + (size_t)b * H_ * KTOT + split * KCHUNK;
    const _Float16* sLo = (dir ? sT_out_lo : sT_in_lo)
                          + (size_t)b * H_ * KTOT + split * KCHUNK;

    for (int i = tid; i < 2048; i += 256) {
        int plane = i >> 10, row = (i >> 5) & 31, c16 = i & 31;
        const _Float16* src = (plane ? sLo : sHi) + (size_t)row * KTOT + c16 * 8;
        half8 v = *(const half8*)src;
        int byte = plane * 16384 + row * 512 + ((c16 * 16) ^ ((row & 7) << 4));
        *(half8*)(smem + byte) = v;
    }
    __syncthreads();

    float* aout = apart + (size_t)(dir * KSPLIT + split) * ASLAB;
    int swz0 = (l15 & 7) << 4;

#pragma unroll 2
    for (int pass = 0; pass < 8; pass++) {
        int n0 = pass * 64;
        const float* mrow = m + ((size_t)b * N_ + n0 + w * 16 + l15) * (2 * KTOT)
                              + (size_t)dir * KTOT + split * KCHUNK;

        f32x4 acc0 = {0.f,0.f,0.f,0.f}, acc1 = {0.f,0.f,0.f,0.f};

#pragma unroll 2
        for (int it = 0; it < 8; it++) {
            int ko = it * 32 + quad * 8;
            f32x4 a0 = *(const f32x4*)(mrow + ko);
            f32x4 a1 = *(const f32x4*)(mrow + ko + 4);

            int kb = it * 64 + quad * 16;
            int o0 = l15 * 512        + (kb ^ swz0);
            int o1 = (l15 + 16) * 512 + (kb ^ swz0);
            half8 Bhi0 = *(const half8*)(smem + o0);
            half8 Bhi1 = *(const half8*)(smem + o1);
            half8 Blo0 = *(const half8*)(smem + 16384 + o0);
            half8 Blo1 = *(const half8*)(smem + 16384 + o1);

            half8 Ahi, Alo;
#pragma unroll
            for (int j = 0; j < 4; j++) {
                float v0 = a0[j], v1 = a1[j];
                _Float16 h0 = (_Float16)v0, h1 = (_Float16)v1;
                Ahi[j]     = h0;
                Ahi[j + 4] = h1;
                Alo[j]     = (_Float16)(v0 - (float)h0);
                Alo[j + 4] = (_Float16)(v1 - (float)h1);
            }
            acc0 = __builtin_amdgcn_mfma_f32_16x16x32_f16(Ahi, Bhi0, acc0, 0, 0, 0);
            acc1 = __builtin_amdgcn_mfma_f32_16x16x32_f16(Ahi, Bhi1, acc1, 0, 0, 0);
            acc0 = __builtin_amdgcn_mfma_f32_16x16x32_f16(Ahi, Blo0, acc0, 0, 0, 0);
            acc1 = __builtin_amdgcn_mfma_f32_16x16x32_f16(Ahi, Blo1, acc1, 0, 0, 0);
            acc0 = __builtin_amdgcn_mfma_f32_16x16x32_f16(Alo, Bhi0, acc0, 0, 0, 0);
            acc1 = __builtin_amdgcn_mfma_f32_16x16x32_f16(Alo, Bhi1, acc1, 0, 0, 0);
        }

#pragma unroll
        for (int r = 0; r < 4; r++) {
            size_t rr = (size_t)b * N_ + (n0 + w * 16 + quad * 4 + r);
            aout[rr * H_ + l15]      = acc0[r];
            aout[rr * H_ + 16 + l15] = acc1[r];
        }
    }
}

__global__ __launch_bounds__(256) void k_gate(const float* __restrict__ apart,
                                              float* __restrict__ hstate,
                                              const float* __restrict__ Wz,
                                              const float* __restrict__ bz,
                                              const float* __restrict__ Wr,
                                              const float* __restrict__ br,
                                              const float* __restrict__ Wt,
                                              const float* __restrict__ bt) {
    __shared__ float cat[8][96];
    __shared__ float rh[8][32];
    int base = blockIdx.x * 8;
    int t = threadIdx.x;

    for (int idx = t; idx < 768; idx += 256) {
        int r = idx / 96, c = idx - r * 96;
        size_t row = (size_t)(base + r);
        float v;
        if (c < 64) {
            int d = c >> 5;
            const float* p = apart + (size_t)d * KSPLIT * ASLAB + row * 32 + (c & 31);
            v = p[0];
#pragma unroll
            for (int s2 = 1; s2 < KSPLIT; s2++) v += p[(size_t)s2 * ASLAB];
        } else {
            v = hstate[row * 32 + (c - 64)];
        }
        cat[r][c] = v;
    }
    __syncthreads();

    int r = t >> 5, i = t & 31;
    float az = bz[i], ar = br[i];
    const f32x4* wzr = (const f32x4*)(Wz + (size_t)i * 96);
    const f32x4* wrr = (const f32x4*)(Wr + (size_t)i * 96);
    const f32x4* crow = (const f32x4*)cat[r];
#pragma unroll
    for (int kc = 0; kc < 24; kc++) {
        f32x4 cv = crow[kc];
        f32x4 wz = wzr[kc];
        f32x4 wr = wrr[kc];
        az += cv[0]*wz[0] + cv[1]*wz[1] + cv[2]*wz[2] + cv[3]*wz[3];
        ar += cv[0]*wr[0] + cv[1]*wr[1] + cv[2]*wr[2] + cv[3]*wr[3];
    }
    float z  = 1.f / (1.f + __expf(-az));
    float rg = 1.f / (1.f + __expf(-ar));
    float hold = cat[r][64 + i];
    rh[r][i] = rg * hold;
    __syncthreads();

    float at = bt[i];
    const f32x4* wtr = (const f32x4*)(Wt + (size_t)i * 96);
#pragma unroll
    for (int kc = 0; kc < 16; kc++) {
        f32x4 cv = crow[kc];
        f32x4 wt = wtr[kc];
        at += cv[0]*wt[0] + cv[1]*wt[1] + cv[2]*wt[2] + cv[3]*wt[3];
    }
    const f32x4* rrow = (const f32x4*)rh[r];
#pragma unroll
    for (int kc = 0; kc < 8; kc++) {
        f32x4 cv = rrow[kc];
        f32x4 wt = wtr[16 + kc];
        at += cv[0]*wt[0] + cv[1]*wt[1] + cv[2]*wt[2] + cv[3]*wt[3];
    }
    float hh = tanhf(at);
    hstate[(size_t)(base + r) * 32 + i] = (1.f - z) * hold + z * hh;
}

__global__ __launch_bounds__(256) void k_final(const float* __restrict__ hstate,
                                               const float* __restrict__ a,
                                               const float* __restrict__ W1,
                                               const float* __restrict__ b1,
                                               const float* __restrict__ W2,
                                               const float* __restrict__ b2,
                                               float* __restrict__ out) {
    __shared__ float hl[8][32];
    __shared__ float as[8];
    int base = blockIdx.x * 8;
    int t = threadIdx.x;
    {
        int r = t >> 5, c = t & 31;
        hl[r][c] = hstate[(size_t)(base + r) * 32 + c];
        if (t < 8) as[t] = a[base + t];
    }
    __syncthreads();
    int r = t >> 5, j = t & 31;
    float acc = b1[j];
    const float* w1r = W1 + (size_t)j * 33;
#pragma unroll
    for (int i2 = 0; i2 < 32; i2++) acc += hl[r][i2] * w1r[i2];
    acc += as[r] * w1r[32];
    float o = tanhf(acc) * W2[j];
#pragma unroll
    for (int off = 16; off; off >>= 1) o += __shfl_xor(o, off, 32);
    if (j == 0) out[base + r] = o + b2[0];
}

// ---------------------------------------------------------------- launcher
extern "C" void kernel_launch(void* const* d_in, const int* in_sizes, int n_in,
                              void* d_out, int out_size, void* d_ws, size_t ws_size,
                              hipStream_t stream) {
    const float* x     = (const float*)d_in[0];
    const float* a     = (const float*)d_in[1];
    const float* m     = (const float*)d_in[2];
    const float* W_in  = (const float*)d_in[3];
    const float* b_in  = (const float*)d_in[4];
    const float* W_out = (const float*)d_in[5];
    const float* b_out = (const float*)d_in[6];
    const float* Wz    = (const float*)d_in[7];
    const float* bz    = (const float*)d_in[8];
    const float* Wr    = (const float*)d_in[9];
    const float* br    = (const float*)d_in[10];
    const float* Wt    = (const float*)d_in[11];
    const float* bt    = (const float*)d_in[12];
    const float* W1    = (const float*)d_in[13];
    const float* b1    = (const float*)d_in[14];
    const float* W2    = (const float*)d_in[15];
    const float* b2    = (const float*)d_in[16];
    float* out = (float*)d_out;

    char* ws = (char*)d_ws;
    float* h = (float*)(ws);                                      // 4 MB

    P2 prm;
    prm.x = x; prm.a = a; prm.m = m;
    prm.W_in = W_in; prm.b_in = b_in; prm.W_out = W_out; prm.b_out = b_out;
    prm.Wz = Wz; prm.bz = bz; prm.Wr = Wr; prm.br = br; prm.Wt = Wt; prm.bt = bt;
    prm.W1 = W1; prm.b1 = b1; prm.W2 = W2; prm.b2 = b2;
    prm.out = out; prm.h = h;

    static int coop_ok = -1;
    if (coop_ok < 0) {
        int v = 0;
        hipDeviceGetAttribute(&v, hipDeviceAttributeCooperativeLaunch, 0);
        coop_ok = v;
    }

    hipError_t err = hipErrorUnknown;
    if (coop_ok) {
        void* args[] = { (void*)&prm };
        err = hipLaunchCooperativeKernel((const void*)k_steps,
                                         dim3(256), dim3(1024), args, 0, stream);
    }
    if (err != hipSuccess) {
        (void)hipGetLastError();   // clear; run proven round-4 path
        float*    apart     = (float*)(ws + ((size_t)4  << 20));
        _Float16* sT_in_hi  = (_Float16*)(ws + ((size_t)68 << 20));
        _Float16* sT_in_lo  = (_Float16*)(ws + ((size_t)76 << 20));
        _Float16* sT_out_hi = (_Float16*)(ws + ((size_t)84 << 20));
        _Float16* sT_out_lo = (_Float16*)(ws + ((size_t)92 << 20));

        k_init_h<<<1024, 256, 0, stream>>>(x, h);
        for (int s = 0; s < NSTEPS; s++) {
            k_s<<<512, 256, 0, stream>>>(h, W_in, b_in, W_out, b_out,
                                         sT_in_hi, sT_in_lo, sT_out_hi, sT_out_lo);
            k_einsum_l<<<dim3(KSPLIT, 64, 2), 256, 0, stream>>>(m, sT_in_hi, sT_in_lo,
                                                                sT_out_hi, sT_out_lo,
                                                                apart);
            k_gate<<<4096, 256, 0, stream>>>(apart, h, Wz, bz, Wr, br, Wt, bt);
        }
        k_final<<<4096, 256, 0, stream>>>(h, a, W1, b1, W2, b2, out);
    }
}

// Round 8
// 2182.749 us; speedup vs baseline: 1.3292x; 1.3292x over previous
//
#include <hip/hip_runtime.h>
#include <hip/hip_fp16.h>
#include <math.h>

#define B_ 64
#define N_ 512
#define H_ 32
#define E_ 4
#define NSTEPS 5
#define KTOT 2048       // N_*E_

typedef _Float16 half8 __attribute__((ext_vector_type(8)));
typedef float   f32x4 __attribute__((ext_vector_type(4)));

// async global->LDS, 16B per lane, dest = wave-uniform base + lane*16
__device__ __forceinline__ void gld16(const void* g, void* l) {
    __builtin_amdgcn_global_load_lds(
        (const __attribute__((address_space(1))) void*)g,
        (__attribute__((address_space(3))) void*)l, 16, 0, 0);
}

// ---------------------------------------------------------------- init h <- x
__global__ __launch_bounds__(256) void k_init_h(const float* __restrict__ x,
                                                float* __restrict__ h) {
    int i = blockIdx.x * blockDim.x + threadIdx.x;   // 262144 float4s
    ((f32x4*)h)[i] = ((const f32x4*)x)[i];
}

// ---------------------------------------------------------------- s projection
__global__ __launch_bounds__(256) void k_s(const float* __restrict__ hstate,
                                           const float* __restrict__ W_in,
                                           const float* __restrict__ b_in,
                                           const float* __restrict__ W_out,
                                           const float* __restrict__ b_out,
                                           _Float16* __restrict__ sT_in_hi,
                                           _Float16* __restrict__ sT_in_lo,
                                           _Float16* __restrict__ sT_out_hi,
                                           _Float16* __restrict__ sT_out_lo) {
    int b  = blockIdx.x >> 3;
    int n0 = (blockIdx.x & 7) * 64;
    int lane = threadIdx.x & 63;
    int w = __builtin_amdgcn_readfirstlane((int)(threadIdx.x >> 6)); // 0..3
    int n = n0 + lane;

    const float* hrow = hstate + ((size_t)b * N_ + n) * H_;
    f32x4 hv[8];
#pragma unroll
    for (int c = 0; c < 8; c++) hv[c] = ((const f32x4*)hrow)[c];

#pragma unroll 4
    for (int o = 0; o < 32; o++) {
        int he = w * 32 + o;
        const f32x4* wr = (const f32x4*)(W_in + (size_t)he * H_);
        float acc = b_in[he];
#pragma unroll
        for (int c = 0; c < 8; c++) {
            f32x4 wv = wr[c];
            acc += hv[c][0]*wv[0] + hv[c][1]*wv[1] + hv[c][2]*wv[2] + hv[c][3]*wv[3];
        }
        int hh = he >> 2, e = he & 3;
        size_t idx = ((size_t)b * H_ + hh) * KTOT + e * N_ + n;
        _Float16 hi = (_Float16)acc;
        sT_in_hi[idx] = hi;
        sT_in_lo[idx] = (_Float16)(acc - (float)hi);
    }
#pragma unroll 4
    for (int o = 0; o < 32; o++) {
        int he = w * 32 + o;
        const f32x4* wr = (const f32x4*)(W_out + (size_t)he * H_);
        float acc = b_out[he];
#pragma unroll
        for (int c = 0; c < 8; c++) {
            f32x4 wv = wr[c];
            acc += hv[c][0]*wv[0] + hv[c][1]*wv[1] + hv[c][2]*wv[2] + hv[c][3]*wv[3];
        }
        int hh = he >> 2, e = he & 3;
        size_t idx = ((size_t)b * H_ + hh) * KTOT + e * N_ + n;
        _Float16 hi = (_Float16)acc;
        sT_out_hi[idx] = hi;
        sT_out_lo[idx] = (_Float16)(acc - (float)hi);
    }
}

// ---------------------------------------------------------------- big einsum
// block = (nblk, b, dir): 64 n-rows, full K=2048 in 16 chunks of 128.
// A (m fp32, 32KB/chunk) and B (sT hi/lo, 16KB/chunk) staged to LDS via
// global_load_lds (async, no VGPR dest), double-buffered, 2-phase schedule.
// Source addresses pre-XOR-swizzled (^ (row&7)<<4); ds_reads apply same XOR.
#define BUFA 32768
#define BUFB 16384
__global__ __launch_bounds__(256) void k_einsum_gl(const float* __restrict__ m,
                                                   const _Float16* __restrict__ sT_in_hi,
                                                   const _Float16* __restrict__ sT_in_lo,
                                                   const _Float16* __restrict__ sT_out_hi,
                                                   const _Float16* __restrict__ sT_out_lo,
                                                   float* __restrict__ a_in,
                                                   float* __restrict__ a_out) {
    __shared__ __align__(16) char lds[2 * BUFA + 2 * BUFB];   // 96 KB
    int nblk = blockIdx.x;
    int b    = blockIdx.y;
    int dir  = blockIdx.z;
    int n0   = nblk * 64;
    int tid  = threadIdx.x;
    int w    = tid >> 6;
    int lane = tid & 63;
    int l15  = lane & 15;
    int quad = lane >> 4;

    const char* mBase = (const char*)(m + ((size_t)(b * N_ + n0)) * (2 * KTOT)
                                        + (size_t)dir * KTOT);
    const _Float16* sHi = (dir ? sT_out_hi : sT_in_hi) + (size_t)b * H_ * KTOT;
    const _Float16* sLo = (dir ? sT_out_lo : sT_in_lo) + (size_t)b * H_ * KTOT;
    float* aout = dir ? a_out : a_in;

    // per-wave staging roles
    int bp  = w >> 1;                 // B plane (0=hi,1=lo)
    int brb = (w & 1) << 4;           // B row base (0 or 16)
    const _Float16* sP = bp ? sLo : sHi;

    // stage chunk c into buffer buf
    auto STAGE = [&](int c, int buf) {
        char* dA = lds + buf * BUFA;
        char* dB = lds + 2 * BUFA + buf * BUFB + bp * 8192;
#pragma unroll
        for (int i = 0; i < 8; i++) {                 // A: 2 rows per instr
            int r = (w << 4) + 2 * i + (lane >> 5);
            const char* g = mBase + (size_t)r * (2 * KTOT * 4) + c * 512
                            + (((lane & 31) * 16) ^ ((r & 7) << 4));
            gld16(g, dA + ((w << 4) + 2 * i) * 512);
        }
#pragma unroll
        for (int i = 0; i < 4; i++) {                 // B: 4 rows per instr
            int r = brb + 4 * i + (lane >> 4);
            const char* g = (const char*)(sP + (size_t)r * KTOT) + c * 256
                            + (((lane & 15) * 16) ^ ((r & 7) << 4));
            gld16(g, dB + (brb + 4 * i) * 256);
        }
    };

    f32x4 acc0 = {0.f,0.f,0.f,0.f}, acc1 = {0.f,0.f,0.f,0.f};

    int rowA  = (w << 4) + l15;
    int swzA  = (rowA & 7) << 4;
    int swzB0 = (l15 & 7) << 4;       // rows l15 and l15+16 share row&7

    STAGE(0, 0);
    __syncthreads();                   // drains vmcnt

    for (int c = 0; c < 16; c++) {
        int buf = c & 1;
        if (c < 15) STAGE(c + 1, buf ^ 1);   // async; flies during compute

        const char* Ab = lds + buf * BUFA + rowA * 512;
        const char* Bh = lds + 2 * BUFA + buf * BUFB;
        const char* Bl = Bh + 8192;
#pragma unroll
        for (int it = 0; it < 4; it++) {
            int kab = it * 128 + quad * 32;          // A byte offset in row
            f32x4 a0 = *(const f32x4*)(Ab + (kab ^ swzA));
            f32x4 a1 = *(const f32x4*)(Ab + ((kab + 16) ^ swzA));

            int kbb = it * 64 + quad * 16;           // B byte offset in row
            int o0 = l15 * 256        + (kbb ^ swzB0);
            int o1 = (l15 + 16) * 256 + (kbb ^ swzB0);
            half8 Bhi0 = *(const half8*)(Bh + o0);
            half8 Bhi1 = *(const half8*)(Bh + o1);
            half8 Blo0 = *(const half8*)(Bl + o0);
            half8 Blo1 = *(const half8*)(Bl + o1);

            half8 Ahi, Alo;
#pragma unroll
            for (int j = 0; j < 4; j++) {
                float v0 = a0[j], v1 = a1[j];
                _Float16 h0 = (_Float16)v0, h1 = (_Float16)v1;
                Ahi[j]     = h0;
                Ahi[j + 4] = h1;
                Alo[j]     = (_Float16)(v0 - (float)h0);
                Alo[j + 4] = (_Float16)(v1 - (float)h1);
            }
            acc0 = __builtin_amdgcn_mfma_f32_16x16x32_f16(Ahi, Bhi0, acc0, 0, 0, 0);
            acc1 = __builtin_amdgcn_mfma_f32_16x16x32_f16(Ahi, Bhi1, acc1, 0, 0, 0);
            acc0 = __builtin_amdgcn_mfma_f32_16x16x32_f16(Ahi, Blo0, acc0, 0, 0, 0);
            acc1 = __builtin_amdgcn_mfma_f32_16x16x32_f16(Ahi, Blo1, acc1, 0, 0, 0);
            acc0 = __builtin_amdgcn_mfma_f32_16x16x32_f16(Alo, Bhi0, acc0, 0, 0, 0);
            acc1 = __builtin_amdgcn_mfma_f32_16x16x32_f16(Alo, Bhi1, acc1, 0, 0, 0);
        }
        __syncthreads();               // drain stage(c+1); protect dbuf
    }

    // D layout: row = quad*4 + r (within 16-row tile), col = l15 (+16 for acc1)
#pragma unroll
    for (int r = 0; r < 4; r++) {
        size_t rr = (size_t)b * N_ + (n0 + w * 16 + quad * 4 + r);
        aout[rr * H_ + l15]      = acc0[r];
        aout[rr * H_ + 16 + l15] = acc1[r];
    }
}

// ---------------------------------------------------------------- GRU gates
__global__ __launch_bounds__(256) void k_gate(const float* __restrict__ a_in,
                                              const float* __restrict__ a_out,
                                              float* __restrict__ hstate,
                                              const float* __restrict__ Wz,
                                              const float* __restrict__ bz,
                                              const float* __restrict__ Wr,
                                              const float* __restrict__ br,
                                              const float* __restrict__ Wt,
                                              const float* __restrict__ bt) {
    __shared__ float cat[8][96];
    __shared__ float rh[8][32];
    int base = blockIdx.x * 8;     // flattened row b*512+n
    int t = threadIdx.x;

    for (int idx = t; idx < 768; idx += 256) {
        int r = idx / 96, c = idx - r * 96;
        size_t row = (size_t)(base + r);
        float v;
        if (c < 32)      v = a_in [row * 32 + c];
        else if (c < 64) v = a_out[row * 32 + (c - 32)];
        else             v = hstate[row * 32 + (c - 64)];
        cat[r][c] = v;
    }
    __syncthreads();

    int r = t >> 5, i = t & 31;
    float az = bz[i], ar = br[i];
    const f32x4* wzr = (const f32x4*)(Wz + (size_t)i * 96);
    const f32x4* wrr = (const f32x4*)(Wr + (size_t)i * 96);
    const f32x4* crow = (const f32x4*)cat[r];
#pragma unroll
    for (int kc = 0; kc < 24; kc++) {
        f32x4 cv = crow[kc];
        f32x4 wz = wzr[kc];
        f32x4 wr = wrr[kc];
        az += cv[0]*wz[0] + cv[1]*wz[1] + cv[2]*wz[2] + cv[3]*wz[3];
        ar += cv[0]*wr[0] + cv[1]*wr[1] + cv[2]*wr[2] + cv[3]*wr[3];
    }
    float z  = 1.f / (1.f + __expf(-az));
    float rg = 1.f / (1.f + __expf(-ar));
    float hold = cat[r][64 + i];
    rh[r][i] = rg * hold;
    __syncthreads();

    float at = bt[i];
    const f32x4* wtr = (const f32x4*)(Wt + (size_t)i * 96);
#pragma unroll
    for (int kc = 0; kc < 16; kc++) {     // a_in | a_out part
        f32x4 cv = crow[kc];
        f32x4 wt = wtr[kc];
        at += cv[0]*wt[0] + cv[1]*wt[1] + cv[2]*wt[2] + cv[3]*wt[3];
    }
    const f32x4* rrow = (const f32x4*)rh[r];
#pragma unroll
    for (int kc = 0; kc < 8; kc++) {      // r*h part
        f32x4 cv = rrow[kc];
        f32x4 wt = wtr[16 + kc];
        at += cv[0]*wt[0] + cv[1]*wt[1] + cv[2]*wt[2] + cv[3]*wt[3];
    }
    float hh = tanhf(at);
    hstate[(size_t)(base + r) * 32 + i] = (1.f - z) * hold + z * hh;
}

// ---------------------------------------------------------------- readout
__global__ __launch_bounds__(256) void k_final(const float* __restrict__ hstate,
                                               const float* __restrict__ a,
                                               const float* __restrict__ W1,
                                               const float* __restrict__ b1,
                                               const float* __restrict__ W2,
                                               const float* __restrict__ b2,
                                               float* __restrict__ out) {
    __shared__ float hl[8][32];
    __shared__ float as[8];
    int base = blockIdx.x * 8;
    int t = threadIdx.x;
    {
        int r = t >> 5, c = t & 31;
        hl[r][c] = hstate[(size_t)(base + r) * 32 + c];
        if (t < 8) as[t] = a[base + t];
    }
    __syncthreads();
    int r = t >> 5, j = t & 31;
    float acc = b1[j];
    const float* w1r = W1 + (size_t)j * 33;
#pragma unroll
    for (int i2 = 0; i2 < 32; i2++) acc += hl[r][i2] * w1r[i2];
    acc += as[r] * w1r[32];
    float o = tanhf(acc) * W2[j];
#pragma unroll
    for (int off = 16; off; off >>= 1) o += __shfl_xor(o, off, 32);
    if (j == 0) out[base + r] = o + b2[0];
}

// ---------------------------------------------------------------- launcher
extern "C" void kernel_launch(void* const* d_in, const int* in_sizes, int n_in,
                              void* d_out, int out_size, void* d_ws, size_t ws_size,
                              hipStream_t stream) {
    const float* x     = (const float*)d_in[0];
    const float* a     = (const float*)d_in[1];
    const float* m     = (const float*)d_in[2];
    const float* W_in  = (const float*)d_in[3];
    const float* b_in  = (const float*)d_in[4];
    const float* W_out = (const float*)d_in[5];
    const float* b_out = (const float*)d_in[6];
    const float* Wz    = (const float*)d_in[7];
    const float* bz    = (const float*)d_in[8];
    const float* Wr    = (const float*)d_in[9];
    const float* br    = (const float*)d_in[10];
    const float* Wt    = (const float*)d_in[11];
    const float* bt    = (const float*)d_in[12];
    const float* W1    = (const float*)d_in[13];
    const float* b1    = (const float*)d_in[14];
    const float* W2    = (const float*)d_in[15];
    const float* b2    = (const float*)d_in[16];
    float* out = (float*)d_out;

    char* ws = (char*)d_ws;
    float*    h         = (float*)(ws);                           // 4 MB
    float*    a_in      = (float*)(ws + ((size_t)4  << 20));      // 4 MB
    float*    a_out     = (float*)(ws + ((size_t)8  << 20));      // 4 MB
    _Float16* sT_in_hi  = (_Float16*)(ws + ((size_t)12 << 20));   // 8 MB
    _Float16* sT_in_lo  = (_Float16*)(ws + ((size_t)20 << 20));   // 8 MB
    _Float16* sT_out_hi = (_Float16*)(ws + ((size_t)28 << 20));   // 8 MB
    _Float16* sT_out_lo = (_Float16*)(ws + ((size_t)36 << 20));   // 8 MB (44 MB)

    k_init_h<<<1024, 256, 0, stream>>>(x, h);
    for (int s = 0; s < NSTEPS; s++) {
        k_s<<<512, 256, 0, stream>>>(h, W_in, b_in, W_out, b_out,
                                     sT_in_hi, sT_in_lo, sT_out_hi, sT_out_lo);
        k_einsum_gl<<<dim3(8, 64, 2), 256, 0, stream>>>(m, sT_in_hi, sT_in_lo,
                                                        sT_out_hi, sT_out_lo,
                                                        a_in, a_out);
        k_gate<<<4096, 256, 0, stream>>>(a_in, a_out, h, Wz, bz, Wr, br, Wt, bt);
    }
    k_final<<<4096, 256, 0, stream>>>(h, a, W1, b1, W2, b2, out);
}

// Round 9
// 2176.261 us; speedup vs baseline: 1.3331x; 1.0030x over previous
//
#include <hip/hip_runtime.h>
#include <hip/hip_fp16.h>
#include <math.h>

#define B_ 64
#define N_ 512
#define H_ 32
#define E_ 4
#define NSTEPS 5
#define KTOT 2048       // N_*E_

typedef _Float16 half8 __attribute__((ext_vector_type(8)));
typedef float   f32x4 __attribute__((ext_vector_type(4)));

// async global->LDS, 16B per lane, dest = wave-uniform base + lane*16
__device__ __forceinline__ void gld16(const void* g, void* l) {
    __builtin_amdgcn_global_load_lds(
        (const __attribute__((address_space(1))) void*)g,
        (__attribute__((address_space(3))) void*)l, 16, 0, 0);
}

// ---------------------------------------------------------------- init h <- x
__global__ __launch_bounds__(256) void k_init_h(const float* __restrict__ x,
                                                float* __restrict__ h) {
    int i = blockIdx.x * blockDim.x + threadIdx.x;   // 262144 float4s
    ((f32x4*)h)[i] = ((const f32x4*)x)[i];
}

// ---------------------------------------------------------------- s projection
__global__ __launch_bounds__(256) void k_s(const float* __restrict__ hstate,
                                           const float* __restrict__ W_in,
                                           const float* __restrict__ b_in,
                                           const float* __restrict__ W_out,
                                           const float* __restrict__ b_out,
                                           _Float16* __restrict__ sT_in_hi,
                                           _Float16* __restrict__ sT_in_lo,
                                           _Float16* __restrict__ sT_out_hi,
                                           _Float16* __restrict__ sT_out_lo) {
    int b  = blockIdx.x >> 3;
    int n0 = (blockIdx.x & 7) * 64;
    int lane = threadIdx.x & 63;
    int w = __builtin_amdgcn_readfirstlane((int)(threadIdx.x >> 6)); // 0..3
    int n = n0 + lane;

    const float* hrow = hstate + ((size_t)b * N_ + n) * H_;
    f32x4 hv[8];
#pragma unroll
    for (int c = 0; c < 8; c++) hv[c] = ((const f32x4*)hrow)[c];

#pragma unroll 4
    for (int o = 0; o < 32; o++) {
        int he = w * 32 + o;
        const f32x4* wr = (const f32x4*)(W_in + (size_t)he * H_);
        float acc = b_in[he];
#pragma unroll
        for (int c = 0; c < 8; c++) {
            f32x4 wv = wr[c];
            acc += hv[c][0]*wv[0] + hv[c][1]*wv[1] + hv[c][2]*wv[2] + hv[c][3]*wv[3];
        }
        int hh = he >> 2, e = he & 3;
        size_t idx = ((size_t)b * H_ + hh) * KTOT + e * N_ + n;
        _Float16 hi = (_Float16)acc;
        sT_in_hi[idx] = hi;
        sT_in_lo[idx] = (_Float16)(acc - (float)hi);
    }
#pragma unroll 4
    for (int o = 0; o < 32; o++) {
        int he = w * 32 + o;
        const f32x4* wr = (const f32x4*)(W_out + (size_t)he * H_);
        float acc = b_out[he];
#pragma unroll
        for (int c = 0; c < 8; c++) {
            f32x4 wv = wr[c];
            acc += hv[c][0]*wv[0] + hv[c][1]*wv[1] + hv[c][2]*wv[2] + hv[c][3]*wv[3];
        }
        int hh = he >> 2, e = he & 3;
        size_t idx = ((size_t)b * H_ + hh) * KTOT + e * N_ + n;
        _Float16 hi = (_Float16)acc;
        sT_out_hi[idx] = hi;
        sT_out_lo[idx] = (_Float16)(acc - (float)hi);
    }
}

// ---------------------------------------------------------------- big einsum
// block (XCD-swizzled) = (nblk, b, dir): 64 n-rows, K=2048 in 32 chunks of 64.
// 3-deep async staging via global_load_lds, COUNTED vmcnt (never 0 in loop),
// raw s_barrier pair per chunk (m201 pattern). 24KB/buf x3 = 72KB -> 2 blk/CU.
// XCD swizzle: 8 nblk-blocks sharing one (b,dir) sT slab land on one XCD L2.
#define CHB   256     // chunk bytes per m row (64 floats)
#define BUFA2 16384   // 64 rows x 256B
#define BUFB2 8192    // 2 planes x 32 rows x 128B
#define BUFSZ 24576
#define NCH   32
__global__ __launch_bounds__(256, 2) void k_einsum_p3(const float* __restrict__ m,
                                                      const _Float16* __restrict__ sT_in_hi,
                                                      const _Float16* __restrict__ sT_in_lo,
                                                      const _Float16* __restrict__ sT_out_hi,
                                                      const _Float16* __restrict__ sT_out_lo,
                                                      float* __restrict__ a_in,
                                                      float* __restrict__ a_out) {
    __shared__ __align__(16) char lds[3 * BUFSZ];   // 72 KB
    int bid  = blockIdx.x;                 // 0..1023
    int xcd  = bid & 7, loc = bid >> 3;    // assume id%8 -> XCD (heuristic)
    int pair = xcd * 16 + (loc >> 3);      // (b,dir) stays on one XCD
    int nblk = loc & 7;
    int b    = pair >> 1;
    int dir  = pair & 1;
    int n0   = nblk * 64;
    int tid  = threadIdx.x;
    int w    = tid >> 6;
    int lane = tid & 63;
    int l15  = lane & 15;
    int quad = lane >> 4;

    const char* mBase = (const char*)(m + ((size_t)(b * N_ + n0)) * (2 * KTOT)
                                        + (size_t)dir * KTOT);
    const _Float16* sHi = (dir ? sT_out_hi : sT_in_hi) + (size_t)b * H_ * KTOT;
    const _Float16* sLo = (dir ? sT_out_lo : sT_in_lo) + (size_t)b * H_ * KTOT;
    float* aout = dir ? a_out : a_in;

    // per-wave staging roles
    int bp   = w >> 1;                 // B plane (0=hi,1=lo)
    int brb  = (w & 1) << 4;           // B row base (0 or 16)
    const char* sP = (const char*)(bp ? sLo : sHi);

    // stage chunk c into buffer buf: 6 gld16 per wave (A:4, B:2)
    auto STAGE = [&](int c, int buf) {
        char* dA = lds + buf * BUFSZ;
        char* dB = lds + buf * BUFSZ + BUFA2 + bp * 4096;
#pragma unroll
        for (int i = 0; i < 4; i++) {                 // A: 4 rows per instr
            int r = (w << 4) + i * 4 + (lane >> 4);
            const char* g = mBase + (size_t)r * (2 * KTOT * 4) + c * CHB
                            + (((lane & 15) * 16) ^ ((r & 7) << 4));
            gld16(g, dA + ((w << 4) + i * 4) * 256);
        }
#pragma unroll
        for (int i = 0; i < 2; i++) {                 // B: 8 rows per instr
            int r = brb + i * 8 + (lane >> 3);
            const char* g = sP + (size_t)r * (KTOT * 2) + c * 128
                            + (((lane & 7) * 16) ^ ((r & 7) << 4));
            gld16(g, dB + (brb + i * 8) * 128);
        }
    };

    f32x4 acc0 = {0.f,0.f,0.f,0.f}, acc1 = {0.f,0.f,0.f,0.f};

    int rowA  = (w << 4) + l15;
    int swzA  = (rowA & 7) << 4;
    int swzB0 = (l15 & 7) << 4;        // rows l15 and l15+16 share row&7

    STAGE(0, 0);
    STAGE(1, 1);

    for (int c = 0; c < NCH; c++) {
        int buf = c % 3;
        if (c + 2 < NCH) STAGE(c + 2, (c + 2) % 3);
        // counted wait: only chunk c's loads must have landed (2 stages stay
        // in flight). 6 loads/wave/stage.
        if (c + 2 < NCH)      asm volatile("s_waitcnt vmcnt(12)" ::: "memory");
        else if (c + 1 < NCH) asm volatile("s_waitcnt vmcnt(6)"  ::: "memory");
        else                  asm volatile("s_waitcnt vmcnt(0)"  ::: "memory");
        __builtin_amdgcn_s_barrier();
        __builtin_amdgcn_sched_barrier(0);

        const char* Ab = lds + buf * BUFSZ + rowA * 256;
        const char* Bh = lds + buf * BUFSZ + BUFA2;
        const char* Bl = Bh + 4096;
#pragma unroll
        for (int it = 0; it < 2; it++) {
            int kab = it * 128 + quad * 32;          // A byte offset in row
            f32x4 a0 = *(const f32x4*)(Ab + (kab ^ swzA));
            f32x4 a1 = *(const f32x4*)(Ab + ((kab + 16) ^ swzA));

            int kbb = it * 64 + quad * 16;           // B byte offset in row
            int o0 = l15 * 128        + (kbb ^ swzB0);
            int o1 = (l15 + 16) * 128 + (kbb ^ swzB0);
            half8 Bhi0 = *(const half8*)(Bh + o0);
            half8 Bhi1 = *(const half8*)(Bh + o1);
            half8 Blo0 = *(const half8*)(Bl + o0);
            half8 Blo1 = *(const half8*)(Bl + o1);

            half8 Ahi, Alo;
#pragma unroll
            for (int j = 0; j < 4; j++) {
                float v0 = a0[j], v1 = a1[j];
                _Float16 h0 = (_Float16)v0, h1 = (_Float16)v1;
                Ahi[j]     = h0;
                Ahi[j + 4] = h1;
                Alo[j]     = (_Float16)(v0 - (float)h0);
                Alo[j + 4] = (_Float16)(v1 - (float)h1);
            }
            acc0 = __builtin_amdgcn_mfma_f32_16x16x32_f16(Ahi, Bhi0, acc0, 0, 0, 0);
            acc1 = __builtin_amdgcn_mfma_f32_16x16x32_f16(Ahi, Bhi1, acc1, 0, 0, 0);
            acc0 = __builtin_amdgcn_mfma_f32_16x16x32_f16(Ahi, Blo0, acc0, 0, 0, 0);
            acc1 = __builtin_amdgcn_mfma_f32_16x16x32_f16(Ahi, Blo1, acc1, 0, 0, 0);
            acc0 = __builtin_amdgcn_mfma_f32_16x16x32_f16(Alo, Bhi0, acc0, 0, 0, 0);
            acc1 = __builtin_amdgcn_mfma_f32_16x16x32_f16(Alo, Bhi1, acc1, 0, 0, 0);
        }
        __builtin_amdgcn_sched_barrier(0);
        __builtin_amdgcn_s_barrier();   // all waves done reading buf before
                                        // next iter's STAGE overwrites it
    }

    // D layout: row = quad*4 + r (within 16-row tile), col = l15 (+16 for acc1)
#pragma unroll
    for (int r = 0; r < 4; r++) {
        size_t rr = (size_t)b * N_ + (n0 + w * 16 + quad * 4 + r);
        aout[rr * H_ + l15]      = acc0[r];
        aout[rr * H_ + 16 + l15] = acc1[r];
    }
}

// ---------------------------------------------------------------- GRU gates
__global__ __launch_bounds__(256) void k_gate(const float* __restrict__ a_in,
                                              const float* __restrict__ a_out,
                                              float* __restrict__ hstate,
                                              const float* __restrict__ Wz,
                                              const float* __restrict__ bz,
                                              const float* __restrict__ Wr,
                                              const float* __restrict__ br,
                                              const float* __restrict__ Wt,
                                              const float* __restrict__ bt) {
    __shared__ float cat[8][96];
    __shared__ float rh[8][32];
    int base = blockIdx.x * 8;     // flattened row b*512+n
    int t = threadIdx.x;

    for (int idx = t; idx < 768; idx += 256) {
        int r = idx / 96, c = idx - r * 96;
        size_t row = (size_t)(base + r);
        float v;
        if (c < 32)      v = a_in [row * 32 + c];
        else if (c < 64) v = a_out[row * 32 + (c - 32)];
        else             v = hstate[row * 32 + (c - 64)];
        cat[r][c] = v;
    }
    __syncthreads();

    int r = t >> 5, i = t & 31;
    float az = bz[i], ar = br[i];
    const f32x4* wzr = (const f32x4*)(Wz + (size_t)i * 96);
    const f32x4* wrr = (const f32x4*)(Wr + (size_t)i * 96);
    const f32x4* crow = (const f32x4*)cat[r];
#pragma unroll
    for (int kc = 0; kc < 24; kc++) {
        f32x4 cv = crow[kc];
        f32x4 wz = wzr[kc];
        f32x4 wr = wrr[kc];
        az += cv[0]*wz[0] + cv[1]*wz[1] + cv[2]*wz[2] + cv[3]*wz[3];
        ar += cv[0]*wr[0] + cv[1]*wr[1] + cv[2]*wr[2] + cv[3]*wr[3];
    }
    float z  = 1.f / (1.f + __expf(-az));
    float rg = 1.f / (1.f + __expf(-ar));
    float hold = cat[r][64 + i];
    rh[r][i] = rg * hold;
    __syncthreads();

    float at = bt[i];
    const f32x4* wtr = (const f32x4*)(Wt + (size_t)i * 96);
#pragma unroll
    for (int kc = 0; kc < 16; kc++) {     // a_in | a_out part
        f32x4 cv = crow[kc];
        f32x4 wt = wtr[kc];
        at += cv[0]*wt[0] + cv[1]*wt[1] + cv[2]*wt[2] + cv[3]*wt[3];
    }
    const f32x4* rrow = (const f32x4*)rh[r];
#pragma unroll
    for (int kc = 0; kc < 8; kc++) {      // r*h part
        f32x4 cv = rrow[kc];
        f32x4 wt = wtr[16 + kc];
        at += cv[0]*wt[0] + cv[1]*wt[1] + cv[2]*wt[2] + cv[3]*wt[3];
    }
    float hh = tanhf(at);
    hstate[(size_t)(base + r) * 32 + i] = (1.f - z) * hold + z * hh;
}

// ---------------------------------------------------------------- readout
__global__ __launch_bounds__(256) void k_final(const float* __restrict__ hstate,
                                               const float* __restrict__ a,
                                               const float* __restrict__ W1,
                                               const float* __restrict__ b1,
                                               const float* __restrict__ W2,
                                               const float* __restrict__ b2,
                                               float* __restrict__ out) {
    __shared__ float hl[8][32];
    __shared__ float as[8];
    int base = blockIdx.x * 8;
    int t = threadIdx.x;
    {
        int r = t >> 5, c = t & 31;
        hl[r][c] = hstate[(size_t)(base + r) * 32 + c];
        if (t < 8) as[t] = a[base + t];
    }
    __syncthreads();
    int r = t >> 5, j = t & 31;
    float acc = b1[j];
    const float* w1r = W1 + (size_t)j * 33;
#pragma unroll
    for (int i2 = 0; i2 < 32; i2++) acc += hl[r][i2] * w1r[i2];
    acc += as[r] * w1r[32];
    float o = tanhf(acc) * W2[j];
#pragma unroll
    for (int off = 16; off; off >>= 1) o += __shfl_xor(o, off, 32);
    if (j == 0) out[base + r] = o + b2[0];
}

// ---------------------------------------------------------------- launcher
extern "C" void kernel_launch(void* const* d_in, const int* in_sizes, int n_in,
                              void* d_out, int out_size, void* d_ws, size_t ws_size,
                              hipStream_t stream) {
    const float* x     = (const float*)d_in[0];
    const float* a     = (const float*)d_in[1];
    const float* m     = (const float*)d_in[2];
    const float* W_in  = (const float*)d_in[3];
    const float* b_in  = (const float*)d_in[4];
    const float* W_out = (const float*)d_in[5];
    const float* b_out = (const float*)d_in[6];
    const float* Wz    = (const float*)d_in[7];
    const float* bz    = (const float*)d_in[8];
    const float* Wr    = (const float*)d_in[9];
    const float* br    = (const float*)d_in[10];
    const float* Wt    = (const float*)d_in[11];
    const float* bt    = (const float*)d_in[12];
    const float* W1    = (const float*)d_in[13];
    const float* b1    = (const float*)d_in[14];
    const float* W2    = (const float*)d_in[15];
    const float* b2    = (const float*)d_in[16];
    float* out = (float*)d_out;

    char* ws = (char*)d_ws;
    float*    h         = (float*)(ws);                           // 4 MB
    float*    a_in      = (float*)(ws + ((size_t)4  << 20));      // 4 MB
    float*    a_out     = (float*)(ws + ((size_t)8  << 20));      // 4 MB
    _Float16* sT_in_hi  = (_Float16*)(ws + ((size_t)12 << 20));   // 8 MB
    _Float16* sT_in_lo  = (_Float16*)(ws + ((size_t)20 << 20));   // 8 MB
    _Float16* sT_out_hi = (_Float16*)(ws + ((size_t)28 << 20));   // 8 MB
    _Float16* sT_out_lo = (_Float16*)(ws + ((size_t)36 << 20));   // 8 MB (44 MB)

    k_init_h<<<1024, 256, 0, stream>>>(x, h);
    for (int s = 0; s < NSTEPS; s++) {
        k_s<<<512, 256, 0, stream>>>(h, W_in, b_in, W_out, b_out,
                                     sT_in_hi, sT_in_lo, sT_out_hi, sT_out_lo);
        k_einsum_p3<<<1024, 256, 0, stream>>>(m, sT_in_hi, sT_in_lo,
                                              sT_out_hi, sT_out_lo,
                                              a_in, a_out);
        k_gate<<<4096, 256, 0, stream>>>(a_in, a_out, h, Wz, bz, Wr, br, Wt, bt);
    }
    k_final<<<4096, 256, 0, stream>>>(h, a, W1, b1, W2, b2, out);
}